// Round 10
// baseline (3685.575 us; speedup 1.0000x reference)
//
#include <hip/hip_runtime.h>
#include <math.h>

// Problem constants (match reference)
#define NN 200000
#define EE 300000
#define BB 64
#define INV_SQRT_D 0.17677669529663687f

// ---- workspace layout in 4-byte words. Total ≈ 57.45M words = 229.8 MB.
// ws budget is ~256MB-class (252 passed, 329 faulted) -> stay <= 252 MB.
#define OFF_H    ((size_t)0)                    // [N][128] f32 node features
#define OFF_PQ   ((size_t)25600000)             // [N][64] uint (bf16x2): q, then vt_r planes
#define OFF_PK   ((size_t)38400000)             // [N][64] uint (bf16x2): kt_r, then As accumulator
#define OFF_S    ((size_t)51200000)             // [3][E][4] f32 scores -> alpha (CSR order)
#define OFF_RP   ((size_t)54800000)             // [3][N+1] int rowptr (padded 600016)
#define OFF_CSRC ((size_t)55400016)             // [3][E] int src per CSR position
#define OFF_CDST ((size_t)56300016)             // [3][E] int dst per CSR position
#define OFF_WF   ((size_t)57200016)             // 14 x [128][128] f32 folded weights
#define OFF_BF   ((size_t)57429392)             // 14 x [128] f32 folded bias
#define OFF_BS   ((size_t)57431184)             // scan block sums 3*128 int
#define OFF_POOL ((size_t)57431568)             // psum [B][256] + pcnt [B][2] (16512)

#define SCAN_L   (NN + 1)
#define SCAN_E   8
#define SCAN_EPB (256 * SCAN_E)                          // 2048
#define SCAN_NB  ((SCAN_L + SCAN_EPB - 1) / SCAN_EPB)    // 98

__device__ __forceinline__ float gelu_exact(float v) {
    return 0.5f * v * (1.0f + erff(v * 0.70710678118654752f));
}
__device__ __forceinline__ float bflo(unsigned u) { return __uint_as_float(u << 16); }
__device__ __forceinline__ float bfhi(unsigned u) { return __uint_as_float(u & 0xffff0000u); }
__device__ __forceinline__ unsigned bfpack(float a, float b) {
    unsigned ua = __float_as_uint(a); ua += 0x7fffu + ((ua >> 16) & 1u);
    unsigned ub = __float_as_uint(b); ub += 0x7fffu + ((ub >> 16) & 1u);
    return (ua >> 16) | (ub & 0xffff0000u);
}

// ---- fold weights. 14 slots: per layer l: [l*7+0]=q copy, [l*7+1+r]=k@Wk_rel[r],
//      [l*7+4+r]=v@Wv_rel[r].  kqv split order is k|q|v (cols 0/128/256).
__global__ __launch_bounds__(256) void fold_weights(
    const float* __restrict__ Wkqv, const float* __restrict__ bkqv,
    const float* __restrict__ Wk_rel, const float* __restrict__ Wv_rel,
    float* __restrict__ Wf, float* __restrict__ bf)
{
    __shared__ float Wr[4096];
    const int b = blockIdx.x, t = threadIdx.x;
    const int l = b / 7, s = b % 7;
    const float* Wq = Wkqv + (size_t)l * 49152;   // [128][384]
    if (s == 0) {
        for (int i = t; i < 16384; i += 256) {
            int kk = i >> 7, c = i & 127;
            Wf[(size_t)b * 16384 + i] = Wq[kk * 384 + 128 + c];
        }
        if (t < 128) bf[b * 128 + t] = bkqv[l * 384 + 128 + t];
    } else {
        const int side = (s - 1) / 3, r = (s - 1) % 3;
        const int off = side ? 256 : 0;
        const float* Wrel = (side ? Wv_rel : Wk_rel) + (size_t)(l * 3 + r) * 4096;
        for (int i = t; i < 4096; i += 256) Wr[i] = Wrel[i];
        __syncthreads();
        for (int i = t; i < 16384; i += 256) {
            int kk = i >> 7, c = i & 127, hh = c >> 5, f = c & 31;
            const float* wrow = Wq + kk * 384 + off + hh * 32;
            const float* wr = Wr + hh * 1024 + f;
            float sum = 0.f;
#pragma unroll
            for (int d = 0; d < 32; ++d) sum += wrow[d] * wr[d * 32];
            Wf[(size_t)b * 16384 + i] = sum;
        }
        if (t < 128) {
            int hh = t >> 5, f = t & 31;
            float sum = 0.f;
#pragma unroll
            for (int d = 0; d < 32; ++d)
                sum += bkqv[l * 384 + off + hh * 32 + d] * Wr[hh * 1024 + d * 32 + f];
            bf[b * 128 + t] = sum;
        }
    }
}

// ---------------- input projection: h = [emb[ast], x] @ Win + bin ----------------
__global__ __launch_bounds__(256) void input_proj(
    const float* __restrict__ x, const int* __restrict__ ast,
    const float* __restrict__ emb, const float* __restrict__ Win,
    const float* __restrict__ bin_, float* __restrict__ h)
{
    __shared__ float Ws[69 * 128];
    __shared__ float As[16 * 70];
    const int t = threadIdx.x;
    const int n0 = blockIdx.x * 16;
    for (int i = t; i < 69 * 128; i += 256) Ws[i] = Win[i];
    for (int i = t; i < 16 * 69; i += 256) {
        int nl = i / 69, kk = i - nl * 69;
        int n = n0 + nl;
        float v = (kk < 64) ? emb[ast[n] * 64 + kk] : x[n * 5 + (kk - 64)];
        As[nl * 70 + kk] = v;
    }
    __syncthreads();
    const int c = t & 127;
    const int nh = (t >> 7) * 8;
    float acc[8];
    float bv = bin_[c];
#pragma unroll
    for (int j = 0; j < 8; ++j) acc[j] = bv;
    for (int k = 0; k < 69; ++k) {
        float w = Ws[k * 128 + c];
#pragma unroll
        for (int j = 0; j < 8; ++j) acc[j] += As[(nh + j) * 70 + k] * w;
    }
#pragma unroll
    for (int j = 0; j < 8; ++j) h[(size_t)(n0 + nh + j) * 128 + c] = acc[j];
}

// ---- CSR build: histogram -> scan -> scatter ----
__global__ __launch_bounds__(256) void csr_hist(
    const int* __restrict__ ei0, const int* __restrict__ ei1, const int* __restrict__ ei2,
    int* __restrict__ rp)
{
    int idx = blockIdx.x * 256 + threadIdx.x;
    if (idx >= 3 * EE) return;
    int r = idx / EE, e = idx - r * EE;
    const int* ei = (r == 0) ? ei0 : ((r == 1) ? ei1 : ei2);
    atomicAdd(&rp[r * SCAN_L + ei[EE + e] + 1], 1);
}

__global__ __launch_bounds__(256) void scan1(int* __restrict__ rp, int* __restrict__ bs)
{
    __shared__ int ts[256];
    const int r = blockIdx.y;
    int* a = rp + (size_t)r * SCAN_L;
    const int base = blockIdx.x * SCAN_EPB + threadIdx.x * SCAN_E;
    int v[SCAN_E];
    int tot = 0;
#pragma unroll
    for (int j = 0; j < SCAN_E; ++j) {
        int idx = base + j;
        v[j] = (idx < SCAN_L) ? a[idx] : 0;
        tot += v[j];
    }
    ts[threadIdx.x] = tot;
    __syncthreads();
    for (int st = 1; st < 256; st <<= 1) {
        int add = (threadIdx.x >= st) ? ts[threadIdx.x - st] : 0;
        __syncthreads();
        ts[threadIdx.x] += add;
        __syncthreads();
    }
    int run = ts[threadIdx.x] - tot;
#pragma unroll
    for (int j = 0; j < SCAN_E; ++j) {
        run += v[j];
        int idx = base + j;
        if (idx < SCAN_L) a[idx] = run;
    }
    if (threadIdx.x == 255) bs[r * 128 + blockIdx.x] = ts[255];
}

__global__ __launch_bounds__(128) void scan2(int* __restrict__ bs)
{
    __shared__ int ts[128];
    const int r = blockIdx.x, t = threadIdx.x;
    int v = (t < SCAN_NB) ? bs[r * 128 + t] : 0;
    ts[t] = v;
    __syncthreads();
    for (int st = 1; st < 128; st <<= 1) {
        int add = (t >= st) ? ts[t - st] : 0;
        __syncthreads();
        ts[t] += add;
        __syncthreads();
    }
    bs[r * 128 + t] = ts[t];
}

__global__ __launch_bounds__(256) void scan3(int* __restrict__ rp, const int* __restrict__ bs)
{
    const int r = blockIdx.y;
    if (blockIdx.x == 0) return;
    const int off = bs[r * 128 + blockIdx.x - 1];
    const int base = blockIdx.x * SCAN_EPB + threadIdx.x * SCAN_E;
    int* a = rp + (size_t)r * SCAN_L;
#pragma unroll
    for (int j = 0; j < SCAN_E; ++j) {
        int idx = base + j;
        if (idx < SCAN_L) a[idx] += off;
    }
}

__global__ __launch_bounds__(256) void csr_scatter(
    const int* __restrict__ ei0, const int* __restrict__ ei1, const int* __restrict__ ei2,
    const int* __restrict__ rp, int* __restrict__ fill,
    int* __restrict__ csrc, int* __restrict__ cdst)
{
    int idx = blockIdx.x * 256 + threadIdx.x;
    if (idx >= 3 * EE) return;
    int r = idx / EE, e = idx - r * EE;
    const int* ei = (r == 0) ? ei0 : ((r == 1) ? ei1 : ei2);
    int src = ei[e], dst = ei[EE + e];
    int pos = rp[r * SCAN_L + dst] + atomicAdd(&fill[r * NN + dst], 1);
    csrc[r * EE + pos] = src;
    cdst[r * EE + pos] = dst;
}

// ---- N x 128 @ 128 x 128 + bias -> bf16x2 plane [N][64] uint. 4x4 register tile. ----
__global__ __launch_bounds__(256) void gemm_bf(
    const float* __restrict__ in, const float* __restrict__ W,
    const float* __restrict__ bias, unsigned* __restrict__ outp)
{
    __shared__ float As[32 * 128];    // 16 KB
    __shared__ float Ws[64 * 128];    // 32 KB (K chunked by 64)
    const int t = threadIdx.x;
    const int n0 = blockIdx.x * 32;
    for (int i = t; i < 32 * 32; i += 256) {
        int nl = i >> 5, k4 = i & 31;
        ((float4*)As)[nl * 32 + k4] = *(const float4*)(in + (size_t)(n0 + nl) * 128 + k4 * 4);
    }
    const int cg = t & 31;            // cols 4cg .. 4cg+3
    const int rg = (t >> 5) * 4;      // rows rg .. rg+3
    float4 bv = *(const float4*)(bias + 4 * cg);
    float acc[4][4];
#pragma unroll
    for (int i = 0; i < 4; ++i) {
        acc[i][0] = bv.x; acc[i][1] = bv.y; acc[i][2] = bv.z; acc[i][3] = bv.w;
    }
    for (int kc = 0; kc < 2; ++kc) {
        __syncthreads();
        for (int i = t; i < 64 * 32; i += 256) {
            int k = i >> 5, c4 = i & 31;
            ((float4*)Ws)[i] = *(const float4*)(W + (size_t)(kc * 64 + k) * 128 + c4 * 4);
        }
        __syncthreads();
        const float* Ab = As + kc * 64;
        for (int k = 0; k < 64; ++k) {
            float4 w = ((const float4*)Ws)[k * 32 + cg];
#pragma unroll
            for (int i = 0; i < 4; ++i) {
                float a = Ab[(rg + i) * 128 + k];
                acc[i][0] += a * w.x; acc[i][1] += a * w.y;
                acc[i][2] += a * w.z; acc[i][3] += a * w.w;
            }
        }
    }
#pragma unroll
    for (int i = 0; i < 4; ++i) {
        uint2 u = make_uint2(bfpack(acc[i][0], acc[i][1]), bfpack(acc[i][2], acc[i][3]));
        *(uint2*)(outp + (size_t)(n0 + rg + i) * 64 + 2 * cg) = u;
    }
}

// ---- edge scores: wave-cooperative. 4 edges/wave, 16 lanes/edge, lane = one uint4
//      (contiguous 256-B row gathers -> 4 segments/instr vs 64 scattered 16-B). ----
__global__ __launch_bounds__(256) void edge_scores_w4(
    const unsigned* __restrict__ q_bf, const unsigned* __restrict__ k_bf,
    const int* __restrict__ csrc, const int* __restrict__ cdst,
    const float* __restrict__ p4, float* __restrict__ s_out)
{
    const int wave = (blockIdx.x * 256 + threadIdx.x) >> 6;
    const int lane = threadIdx.x & 63;
    const int e = lane >> 4, j = lane & 15;
    const int p = wave * 4 + e;            // grid sized so p < EE exactly
    int src = csrc[p], dst = cdst[p];
    uint4 q4 = *(const uint4*)(q_bf + (size_t)dst * 64 + 4 * j);
    uint4 k4 = *(const uint4*)(k_bf + (size_t)src * 64 + 4 * j);
    float sum = bflo(q4.x) * bflo(k4.x) + bfhi(q4.x) * bfhi(k4.x)
              + bflo(q4.y) * bflo(k4.y) + bfhi(q4.y) * bfhi(k4.y)
              + bflo(q4.z) * bflo(k4.z) + bfhi(q4.z) * bfhi(k4.z)
              + bflo(q4.w) * bflo(k4.w) + bfhi(q4.w) * bfhi(k4.w);
    sum += __shfl_xor(sum, 1);
    sum += __shfl_xor(sum, 2);             // 4-lane group = one head's 32 dims
    const int hh = j >> 2;
    float val = sum * p4[hh] * INV_SQRT_D;
    if ((j & 3) == 0)
        s_out[(size_t)p * 4 + hh] = val;   // 16 writer lanes -> contiguous 64 B
}

// ---- CSR segment softmax (coalesced, zero indirection) ----
__global__ __launch_bounds__(256) void csr_softmax(
    float* __restrict__ s, const int* __restrict__ rp)
{
    const int dst = blockIdx.x * 4 + (threadIdx.x >> 6);
    const int lane = threadIdx.x & 63;
    const int sub = lane >> 2, hh = lane & 3;
    int beg[3], end[3];
#pragma unroll
    for (int r = 0; r < 3; ++r) {
        beg[r] = rp[r * SCAN_L + dst];
        end[r] = rp[r * SCAN_L + dst + 1];
    }
    float m = -INFINITY;
#pragma unroll
    for (int r = 0; r < 3; ++r)
        for (int p = beg[r] + sub; p < end[r]; p += 16)
            m = fmaxf(m, s[((size_t)r * EE + p) * 4 + hh]);
#pragma unroll
    for (int st = 4; st < 64; st <<= 1) m = fmaxf(m, __shfl_xor(m, st));
    float zz = 0.f;
#pragma unroll
    for (int r = 0; r < 3; ++r)
        for (int p = beg[r] + sub; p < end[r]; p += 16) {
            size_t off = ((size_t)r * EE + p) * 4 + hh;
            float ex = expf(s[off] - m);
            s[off] = ex;
            zz += ex;
        }
#pragma unroll
    for (int st = 4; st < 64; st <<= 1) zz += __shfl_xor(zz, st);
    float inv = 1.f / (zz + 1e-16f);
#pragma unroll
    for (int r = 0; r < 3; ++r)
        for (int p = beg[r] + sub; p < end[r]; p += 16)
            s[((size_t)r * EE + p) * 4 + hh] *= inv;
}

// ---- agg_r: per-relation edge-parallel aggregation of TRANSFORMED vt (Wv_rel folded
//      into the GEMM). LDS f32 accumulate, then bf16 RMW into global As plane.
//      16 dsts/block, LDS 8448 B, no stage-2 transform (that was R9's issue bind). ----
template<int FIRST>
__global__ __launch_bounds__(256, 8) void agg_r(
    const unsigned* __restrict__ vt, const float* __restrict__ s_r,
    const int* __restrict__ rp_r, const int* __restrict__ csrc_r,
    const int* __restrict__ cdst_r, unsigned* __restrict__ As_g)
{
    __shared__ float A[16 * 132];                  // 8448 B

    const int t = threadIdx.x;
    const int n0 = blockIdx.x * 16;
    const int w = t >> 6, lane = t & 63;

    for (int i = t; i < 16 * 132; i += 256) A[i] = 0.f;
    __syncthreads();

    {
        const int hh = lane >> 4;
        const int pcol = 2 * lane + hh;            // padded col (pitch 33/head)
        const int rb = rp_r[n0];
        const int re = rp_r[n0 + 16];
        int p = rb + w;
        for (; p + 4 < re; p += 8) {               // 2-wide pipeline
            int src0 = csrc_r[p];
            int dl0  = cdst_r[p] - n0;
            float al0 = s_r[(size_t)p * 4 + hh];
            int p1 = p + 4;
            int src1 = csrc_r[p1];
            int dl1  = cdst_r[p1] - n0;
            float al1 = s_r[(size_t)p1 * 4 + hh];
            unsigned v0 = vt[(size_t)src0 * 64 + lane];
            unsigned v1 = vt[(size_t)src1 * 64 + lane];
            float* A0 = A + dl0 * 132 + pcol;
            atomicAdd(A0,     al0 * bflo(v0));
            atomicAdd(A0 + 1, al0 * bfhi(v0));
            float* A1 = A + dl1 * 132 + pcol;
            atomicAdd(A1,     al1 * bflo(v1));
            atomicAdd(A1 + 1, al1 * bfhi(v1));
        }
        for (; p < re; p += 4) {
            int src = csrc_r[p];
            int dl  = cdst_r[p] - n0;
            float al = s_r[(size_t)p * 4 + hh];
            unsigned v2 = vt[(size_t)src * 64 + lane];
            float* Ap = A + dl * 132 + pcol;
            atomicAdd(Ap,     al * bflo(v2));
            atomicAdd(Ap + 1, al * bfhi(v2));
        }
    }
    __syncthreads();

    // write / accumulate into global bf16 As plane (owner-exclusive, no atomics)
    for (int i = t; i < 16 * 64; i += 256) {
        int dl = i >> 6, c = i & 63;
        int pc = 2 * c + (c >> 4);
        float a0 = A[dl * 132 + pc];
        float a1 = A[dl * 132 + pc + 1];
        size_t off = (size_t)(n0 + dl) * 64 + c;
        if (FIRST) {
            As_g[off] = bfpack(a0, a1);
        } else {
            unsigned old = As_g[off];
            As_g[off] = bfpack(bflo(old) + a0, bfhi(old) + a1);
        }
    }
}

// ---- out_ln: gelu(As bf16) @ Wout + bout -> skip -> LayerNorm -> h. 32 rows/block ----
__global__ __launch_bounds__(256) void out_ln(
    const unsigned* __restrict__ As_g, float* __restrict__ h,
    const float* __restrict__ Wout, const float* __restrict__ bout,
    const float* __restrict__ skipp, const float* __restrict__ lg,
    const float* __restrict__ lb)
{
    __shared__ float Asl[32 * 130];   // 16640 B (padded pitch 130)
    __shared__ float Ws[64 * 128];    // 32768 B
    const int t = threadIdx.x;
    const int n0 = blockIdx.x * 32;
    for (int i = t; i < 32 * 64; i += 256) {
        int row = i >> 6, j = i & 63;
        unsigned u = As_g[(size_t)(n0 + row) * 64 + j];
        Asl[row * 130 + 2 * j]     = gelu_exact(bflo(u));
        Asl[row * 130 + 2 * j + 1] = gelu_exact(bfhi(u));
    }
    const int cg = t & 31;            // cols 4cg..4cg+3
    const int rg = (t >> 5) * 4;      // rows rg..rg+3
    float4 bv = *(const float4*)(bout + 4 * cg);
    float acc[4][4];
#pragma unroll
    for (int i = 0; i < 4; ++i) {
        acc[i][0] = bv.x; acc[i][1] = bv.y; acc[i][2] = bv.z; acc[i][3] = bv.w;
    }
    for (int kc = 0; kc < 2; ++kc) {
        __syncthreads();
        for (int i = t; i < 64 * 32; i += 256) {
            int k = i >> 5, c4 = i & 31;
            ((float4*)Ws)[i] = *(const float4*)(Wout + (size_t)(kc * 64 + k) * 128 + c4 * 4);
        }
        __syncthreads();
        for (int k = 0; k < 64; ++k) {
            float4 w = ((const float4*)Ws)[k * 32 + cg];
#pragma unroll
            for (int i = 0; i < 4; ++i) {
                float a = Asl[(rg + i) * 130 + kc * 64 + k];
                acc[i][0] += a * w.x; acc[i][1] += a * w.y;
                acc[i][2] += a * w.z; acc[i][3] += a * w.w;
            }
        }
    }
    const float alpha = 1.f / (1.f + expf(-skipp[0]));
    const float om = 1.f - alpha;
    float4 g4 = *(const float4*)(lg + 4 * cg);
    float4 b4 = *(const float4*)(lb + 4 * cg);
#pragma unroll
    for (int i = 0; i < 4; ++i) {
        const size_t n = (size_t)(n0 + rg + i);
        float4 hv = *(const float4*)(h + n * 128 + 4 * cg);
        float o0 = alpha * acc[i][0] + om * hv.x;
        float o1 = alpha * acc[i][1] + om * hv.y;
        float o2 = alpha * acc[i][2] + om * hv.z;
        float o3 = alpha * acc[i][3] + om * hv.w;
        float sm = o0 + o1 + o2 + o3;
#pragma unroll
        for (int m = 1; m < 32; m <<= 1) sm += __shfl_xor(sm, m);
        float mu = sm * (1.f / 128.f);
        float d0 = o0 - mu, d1 = o1 - mu, d2 = o2 - mu, d3 = o3 - mu;
        float sq = d0 * d0 + d1 * d1 + d2 * d2 + d3 * d3;
#pragma unroll
        for (int m = 1; m < 32; m <<= 1) sq += __shfl_xor(sq, m);
        float rs = rsqrtf(sq * (1.f / 128.f) + 1e-5f);
        float4 o = make_float4(d0 * rs * g4.x + b4.x, d1 * rs * g4.y + b4.y,
                               d2 * rs * g4.z + b4.z, d3 * rs * g4.w + b4.w);
        *(float4*)(h + n * 128 + 4 * cg) = o;
    }
}

// ---- parallel masked mean-pool partials (batch sorted -> run-flush) ----
__global__ __launch_bounds__(256) void pool_partial(
    const float* __restrict__ h, const float* __restrict__ x,
    const int* __restrict__ batch, float* __restrict__ psum, float* __restrict__ pcnt)
{
    const int c = threadIdx.x & 127;
    const int n0 = blockIdx.x * 64 + (threadIdx.x >> 7) * 32;
    int g = batch[n0];
    float sw = 0.f, sn = 0.f, cw = 0.f, cn = 0.f;
    for (int i = 0; i < 32; ++i) {
        int n = n0 + i;
        int gn = batch[n];
        if (gn != g) {
            atomicAdd(&psum[g * 256 + c], sw);
            atomicAdd(&psum[g * 256 + 128 + c], sn);
            if (c == 0) { atomicAdd(&pcnt[g * 2], cw); atomicAdd(&pcnt[g * 2 + 1], cn); }
            sw = sn = cw = cn = 0.f;
            g = gn;
        }
        float w = (x[(size_t)n * 5 + 1] > 0.f) ? 1.f : 0.f;
        float hv = h[(size_t)n * 128 + c];
        sw += w * hv; sn += (1.f - w) * hv;
        cw += w; cn += 1.f - w;
    }
    atomicAdd(&psum[g * 256 + c], sw);
    atomicAdd(&psum[g * 256 + 128 + c], sn);
    if (c == 0) { atomicAdd(&pcnt[g * 2], cw); atomicAdd(&pcnt[g * 2 + 1], cn); }
}

// ---------------- MLP head (pool finalize fused) ----------------
__global__ __launch_bounds__(256) void head_kernel(
    const float* __restrict__ psum, const float* __restrict__ pcnt,
    const float* __restrict__ task,
    const float* __restrict__ Wtf, const float* __restrict__ btf,
    const float* __restrict__ Wc1, const float* __restrict__ bc1,
    const float* __restrict__ Wc2, const float* __restrict__ bc2,
    float* __restrict__ out)
{
    __shared__ float in_s[640];
    __shared__ float ge_s[256];
    __shared__ float hc_s[64];
    const int b = blockIdx.x, t = threadIdx.x;
    if (t < 256) {
        float cnt = pcnt[b * 2 + (t >> 7)];
        float sv = psum[b * 256 + t];
        in_s[t] = (cnt > 0.f) ? sv / fmaxf(cnt, 1.f) : 0.f;
    }
    for (int i = t; i < 384; i += 256) in_s[256 + i] = task[b * 384 + i];
    __syncthreads();
    float acc = btf[t];
    for (int i = 0; i < 640; ++i) acc += in_s[i] * Wtf[i * 256 + t];
    ge_s[t] = fmaxf(acc, 0.f);
    __syncthreads();
    if (t < 64) {
        float a2 = bc1[t];
        for (int i = 0; i < 256; ++i) a2 += ge_s[i] * Wc1[i * 64 + t];
        hc_s[t] = fmaxf(a2, 0.f);
    }
    __syncthreads();
    if (t < 64) {
        float v = hc_s[t] * Wc2[t];
#pragma unroll
        for (int off = 32; off >= 1; off >>= 1) v += __shfl_down(v, off);
        if (t == 0) out[b] = v + bc2[0];
    }
}

__global__ __launch_bounds__(256) void zero_kernel(float4* __restrict__ p, int count4)
{
    int i = blockIdx.x * 256 + threadIdx.x;
    if (i < count4) p[i] = make_float4(0.f, 0.f, 0.f, 0.f);
}

extern "C" void kernel_launch(void* const* d_in, const int* in_sizes, int n_in,
                              void* d_out, int out_size, void* d_ws, size_t ws_size,
                              hipStream_t stream)
{
    const float* x      = (const float*)d_in[0];
    const int*   ast    = (const int*)d_in[1];
    const int*   batch  = (const int*)d_in[2];
    const int*   ei[3]  = {(const int*)d_in[3], (const int*)d_in[4], (const int*)d_in[5]};
    const float* task   = (const float*)d_in[6];
    const float* emb    = (const float*)d_in[7];
    const float* Win    = (const float*)d_in[8];
    const float* bin_   = (const float*)d_in[9];
    const float* Wkqv   = (const float*)d_in[10];
    const float* bkqv   = (const float*)d_in[11];
    const float* Wk_rel = (const float*)d_in[12];
    const float* Wv_rel = (const float*)d_in[13];
    const float* p_rel  = (const float*)d_in[14];
    const float* Wout   = (const float*)d_in[15];
    const float* bout   = (const float*)d_in[16];
    const float* skip   = (const float*)d_in[17];
    const float* ln_g   = (const float*)d_in[18];
    const float* ln_b   = (const float*)d_in[19];
    const float* Wtf    = (const float*)d_in[20];
    const float* btf    = (const float*)d_in[21];
    const float* Wc1    = (const float*)d_in[22];
    const float* bc1    = (const float*)d_in[23];
    const float* Wc2    = (const float*)d_in[24];
    const float* bc2    = (const float*)d_in[25];
    float* out = (float*)d_out;
    float* ws  = (float*)d_ws;

    float*    h    = ws + OFF_H;
    unsigned* PQ   = (unsigned*)(ws + OFF_PQ);   // q plane, then vt_r plane
    unsigned* PK   = (unsigned*)(ws + OFF_PK);   // kt_r plane, then As accumulator
    float*    sbuf = ws + OFF_S;
    int*      rp   = (int*)(ws + OFF_RP);
    int*      csrc = (int*)(ws + OFF_CSRC);
    int*      cdst = (int*)(ws + OFF_CDST);
    int*      fill = (int*)(ws + OFF_PQ);        // aliases PQ during CSR build only
    float*    Wf   = ws + OFF_WF;
    float*    bf   = ws + OFF_BF;
    int*      bs   = (int*)(ws + OFF_BS);
    float*    psum = ws + OFF_POOL;
    float*    pcnt = psum + (size_t)BB * 256;

    fold_weights<<<14, 256, 0, stream>>>(Wkqv, bkqv, Wk_rel, Wv_rel, Wf, bf);
    input_proj<<<NN / 16, 256, 0, stream>>>(x, ast, emb, Win, bin_, h);

    zero_kernel<<<(600016 / 4 + 255) / 256, 256, 0, stream>>>((float4*)rp, 600016 / 4);
    zero_kernel<<<(600000 / 4 + 255) / 256, 256, 0, stream>>>((float4*)fill, 600000 / 4);
    csr_hist<<<(3 * EE + 255) / 256, 256, 0, stream>>>(ei[0], ei[1], ei[2], rp);
    scan1<<<dim3(SCAN_NB, 3), 256, 0, stream>>>(rp, bs);
    scan2<<<3, 128, 0, stream>>>(bs);
    scan3<<<dim3(SCAN_NB, 3), 256, 0, stream>>>(rp, bs);
    csr_scatter<<<(3 * EE + 255) / 256, 256, 0, stream>>>(
        ei[0], ei[1], ei[2], rp, fill, csrc, cdst);

    for (int l = 0; l < 2; ++l) {
        const size_t ls = (size_t)l * 7;   // slots: 0=q, 1..3=kt_r, 4..6=vt_r
        gemm_bf<<<NN / 32, 256, 0, stream>>>(h, Wf + ls * 16384, bf + ls * 128, PQ);
        for (int r = 0; r < 3; ++r) {
            gemm_bf<<<NN / 32, 256, 0, stream>>>(
                h, Wf + (ls + 1 + r) * 16384, bf + (ls + 1 + r) * 128, PK);
            edge_scores_w4<<<EE / 16, 256, 0, stream>>>(
                PQ, PK, csrc + (size_t)r * EE, cdst + (size_t)r * EE,
                p_rel + (size_t)(l * 3 + r) * 4, sbuf + (size_t)r * EE * 4);
        }
        csr_softmax<<<NN / 4, 256, 0, stream>>>(sbuf, rp);
        // q dead -> PQ becomes vt_r plane; kt dead -> PK becomes As accumulator
        for (int r = 0; r < 3; ++r) {
            gemm_bf<<<NN / 32, 256, 0, stream>>>(
                h, Wf + (ls + 4 + r) * 16384, bf + (ls + 4 + r) * 128, PQ);
            if (r == 0)
                agg_r<1><<<NN / 16, 256, 0, stream>>>(
                    PQ, sbuf + (size_t)r * EE * 4, rp + (size_t)r * SCAN_L,
                    csrc + (size_t)r * EE, cdst + (size_t)r * EE, PK);
            else
                agg_r<0><<<NN / 16, 256, 0, stream>>>(
                    PQ, sbuf + (size_t)r * EE * 4, rp + (size_t)r * SCAN_L,
                    csrc + (size_t)r * EE, cdst + (size_t)r * EE, PK);
        }
        out_ln<<<NN / 32, 256, 0, stream>>>(
            PK, h, Wout + (size_t)l * 16384, bout + (size_t)l * 128,
            skip + l, ln_g + (size_t)l * 128, ln_b + (size_t)l * 128);
    }

    zero_kernel<<<(16512 / 4 + 255) / 256, 256, 0, stream>>>((float4*)psum, 16512 / 4);
    pool_partial<<<NN / 64, 256, 0, stream>>>(h, x, batch, psum, pcnt);
    head_kernel<<<BB, 256, 0, stream>>>(psum, pcnt, task, Wtf, btf, Wc1, bc1, Wc2, bc2, out);
}

// Round 11
// 2666.986 us; speedup vs baseline: 1.3819x; 1.3819x over previous
//
#include <hip/hip_runtime.h>
#include <math.h>

// Problem constants (match reference)
#define NN 200000
#define EE 300000
#define BB 64
#define INV_SQRT_D 0.17677669529663687f

// ---- workspace layout in 4-byte words. Total ≈ 57.45M words = 229.8 MB.
// ws budget is ~256MB-class (252 passed, 329 faulted) -> stay <= 252 MB.
// h is bf16 now (frees 51 MB -> room for As plane + 2 vt planes live at once).
#define OFF_HB   ((size_t)0)                    // [N][64] uint (bf16x2) node features
#define OFF_P0   ((size_t)12800000)             // [N][64] uint: q, then vt_0, then vt_2
#define OFF_P1   ((size_t)25600000)             // [N][64] uint: kt_r, then vt_1
#define OFF_AS   ((size_t)38400000)             // [N][64] uint: As accumulator (bf16)
#define OFF_S    ((size_t)51200000)             // [3][E][4] f32 scores -> alpha (CSR order)
#define OFF_RP   ((size_t)54800000)             // [3][N+1] int rowptr (padded 600016)
#define OFF_CSRC ((size_t)55400016)             // [3][E] int src per CSR position
#define OFF_CDST ((size_t)56300016)             // [3][E] int dst per CSR position
#define OFF_WF   ((size_t)57200016)             // 14 x [128][128] f32 folded weights
#define OFF_BF   ((size_t)57429392)             // 14 x [128] f32 folded bias
#define OFF_BS   ((size_t)57431184)             // scan block sums 3*128 int
#define OFF_POOL ((size_t)57431568)             // psum [B][256] + pcnt [B][2] (16512)

#define SCAN_L   (NN + 1)
#define SCAN_E   8
#define SCAN_EPB (256 * SCAN_E)                          // 2048
#define SCAN_NB  ((SCAN_L + SCAN_EPB - 1) / SCAN_EPB)    // 98

__device__ __forceinline__ float gelu_exact(float v) {
    return 0.5f * v * (1.0f + erff(v * 0.70710678118654752f));
}
__device__ __forceinline__ float bflo(unsigned u) { return __uint_as_float(u << 16); }
__device__ __forceinline__ float bfhi(unsigned u) { return __uint_as_float(u & 0xffff0000u); }
__device__ __forceinline__ unsigned bfpack(float a, float b) {
    unsigned ua = __float_as_uint(a); ua += 0x7fffu + ((ua >> 16) & 1u);
    unsigned ub = __float_as_uint(b); ub += 0x7fffu + ((ub >> 16) & 1u);
    return (ua >> 16) | (ub & 0xffff0000u);
}

// ---- fold weights. 14 slots: per layer l: [l*7+0]=q copy, [l*7+1+r]=k@Wk_rel[r],
//      [l*7+4+r]=v@Wv_rel[r].  kqv split order is k|q|v (cols 0/128/256).
__global__ __launch_bounds__(256) void fold_weights(
    const float* __restrict__ Wkqv, const float* __restrict__ bkqv,
    const float* __restrict__ Wk_rel, const float* __restrict__ Wv_rel,
    float* __restrict__ Wf, float* __restrict__ bf)
{
    __shared__ float Wr[4096];
    const int b = blockIdx.x, t = threadIdx.x;
    const int l = b / 7, s = b % 7;
    const float* Wq = Wkqv + (size_t)l * 49152;   // [128][384]
    if (s == 0) {
        for (int i = t; i < 16384; i += 256) {
            int kk = i >> 7, c = i & 127;
            Wf[(size_t)b * 16384 + i] = Wq[kk * 384 + 128 + c];
        }
        if (t < 128) bf[b * 128 + t] = bkqv[l * 384 + 128 + t];
    } else {
        const int side = (s - 1) / 3, r = (s - 1) % 3;
        const int off = side ? 256 : 0;
        const float* Wrel = (side ? Wv_rel : Wk_rel) + (size_t)(l * 3 + r) * 4096;
        for (int i = t; i < 4096; i += 256) Wr[i] = Wrel[i];
        __syncthreads();
        for (int i = t; i < 16384; i += 256) {
            int kk = i >> 7, c = i & 127, hh = c >> 5, f = c & 31;
            const float* wrow = Wq + kk * 384 + off + hh * 32;
            const float* wr = Wr + hh * 1024 + f;
            float sum = 0.f;
#pragma unroll
            for (int d = 0; d < 32; ++d) sum += wrow[d] * wr[d * 32];
            Wf[(size_t)b * 16384 + i] = sum;
        }
        if (t < 128) {
            int hh = t >> 5, f = t & 31;
            float sum = 0.f;
#pragma unroll
            for (int d = 0; d < 32; ++d)
                sum += bkqv[l * 384 + off + hh * 32 + d] * Wr[hh * 1024 + d * 32 + f];
            bf[b * 128 + t] = sum;
        }
    }
}

// ---------------- input projection: h_bf = bf16([emb[ast], x] @ Win + bin) ----------------
__global__ __launch_bounds__(256) void input_proj(
    const float* __restrict__ x, const int* __restrict__ ast,
    const float* __restrict__ emb, const float* __restrict__ Win,
    const float* __restrict__ bin_, unsigned* __restrict__ h_bf)
{
    __shared__ float Ws[69 * 128];
    __shared__ float As[16 * 70];
    const int t = threadIdx.x;
    const int n0 = blockIdx.x * 16;
    for (int i = t; i < 69 * 128; i += 256) Ws[i] = Win[i];
    for (int i = t; i < 16 * 69; i += 256) {
        int nl = i / 69, kk = i - nl * 69;
        int n = n0 + nl;
        float v = (kk < 64) ? emb[ast[n] * 64 + kk] : x[n * 5 + (kk - 64)];
        As[nl * 70 + kk] = v;
    }
    __syncthreads();
    const int c2 = t & 63;            // col pair 2c2, 2c2+1
    const int nh = (t >> 6) * 4;      // 4 rows
    float acc0[4], acc1[4];
    float b0 = bin_[2 * c2], b1 = bin_[2 * c2 + 1];
#pragma unroll
    for (int j = 0; j < 4; ++j) { acc0[j] = b0; acc1[j] = b1; }
    for (int k = 0; k < 69; ++k) {
        float w0 = Ws[k * 128 + 2 * c2];
        float w1 = Ws[k * 128 + 2 * c2 + 1];
#pragma unroll
        for (int j = 0; j < 4; ++j) {
            float a = As[(nh + j) * 70 + k];
            acc0[j] += a * w0;
            acc1[j] += a * w1;
        }
    }
#pragma unroll
    for (int j = 0; j < 4; ++j)
        h_bf[(size_t)(n0 + nh + j) * 64 + c2] = bfpack(acc0[j], acc1[j]);
}

// ---- CSR build: histogram -> scan -> scatter ----
__global__ __launch_bounds__(256) void csr_hist(
    const int* __restrict__ ei0, const int* __restrict__ ei1, const int* __restrict__ ei2,
    int* __restrict__ rp)
{
    int idx = blockIdx.x * 256 + threadIdx.x;
    if (idx >= 3 * EE) return;
    int r = idx / EE, e = idx - r * EE;
    const int* ei = (r == 0) ? ei0 : ((r == 1) ? ei1 : ei2);
    atomicAdd(&rp[r * SCAN_L + ei[EE + e] + 1], 1);
}

__global__ __launch_bounds__(256) void scan1(int* __restrict__ rp, int* __restrict__ bs)
{
    __shared__ int ts[256];
    const int r = blockIdx.y;
    int* a = rp + (size_t)r * SCAN_L;
    const int base = blockIdx.x * SCAN_EPB + threadIdx.x * SCAN_E;
    int v[SCAN_E];
    int tot = 0;
#pragma unroll
    for (int j = 0; j < SCAN_E; ++j) {
        int idx = base + j;
        v[j] = (idx < SCAN_L) ? a[idx] : 0;
        tot += v[j];
    }
    ts[threadIdx.x] = tot;
    __syncthreads();
    for (int st = 1; st < 256; st <<= 1) {
        int add = (threadIdx.x >= st) ? ts[threadIdx.x - st] : 0;
        __syncthreads();
        ts[threadIdx.x] += add;
        __syncthreads();
    }
    int run = ts[threadIdx.x] - tot;
#pragma unroll
    for (int j = 0; j < SCAN_E; ++j) {
        run += v[j];
        int idx = base + j;
        if (idx < SCAN_L) a[idx] = run;
    }
    if (threadIdx.x == 255) bs[r * 128 + blockIdx.x] = ts[255];
}

__global__ __launch_bounds__(128) void scan2(int* __restrict__ bs)
{
    __shared__ int ts[128];
    const int r = blockIdx.x, t = threadIdx.x;
    int v = (t < SCAN_NB) ? bs[r * 128 + t] : 0;
    ts[t] = v;
    __syncthreads();
    for (int st = 1; st < 128; st <<= 1) {
        int add = (t >= st) ? ts[t - st] : 0;
        __syncthreads();
        ts[t] += add;
        __syncthreads();
    }
    bs[r * 128 + t] = ts[t];
}

__global__ __launch_bounds__(256) void scan3(int* __restrict__ rp, const int* __restrict__ bs)
{
    const int r = blockIdx.y;
    if (blockIdx.x == 0) return;
    const int off = bs[r * 128 + blockIdx.x - 1];
    const int base = blockIdx.x * SCAN_EPB + threadIdx.x * SCAN_E;
    int* a = rp + (size_t)r * SCAN_L;
#pragma unroll
    for (int j = 0; j < SCAN_E; ++j) {
        int idx = base + j;
        if (idx < SCAN_L) a[idx] += off;
    }
}

__global__ __launch_bounds__(256) void csr_scatter(
    const int* __restrict__ ei0, const int* __restrict__ ei1, const int* __restrict__ ei2,
    const int* __restrict__ rp, int* __restrict__ fill,
    int* __restrict__ csrc, int* __restrict__ cdst)
{
    int idx = blockIdx.x * 256 + threadIdx.x;
    if (idx >= 3 * EE) return;
    int r = idx / EE, e = idx - r * EE;
    const int* ei = (r == 0) ? ei0 : ((r == 1) ? ei1 : ei2);
    int src = ei[e], dst = ei[EE + e];
    int pos = rp[r * SCAN_L + dst] + atomicAdd(&fill[r * NN + dst], 1);
    csrc[r * EE + pos] = src;
    cdst[r * EE + pos] = dst;
}

// ---- N x 128 (bf16 in) @ 128 x 128 (f32 W) + bias -> bf16x2 plane. 4x4 tile. ----
__global__ __launch_bounds__(256) void gemm_bf(
    const unsigned* __restrict__ in_bf, const float* __restrict__ W,
    const float* __restrict__ bias, unsigned* __restrict__ outp)
{
    __shared__ float As[32 * 128];    // 16 KB
    __shared__ float Ws[64 * 128];    // 32 KB (K chunked by 64)
    const int t = threadIdx.x;
    const int n0 = blockIdx.x * 32;
    for (int i = t; i < 32 * 32; i += 256) {
        int nl = i >> 5, u2 = i & 31;
        uint2 u = *(const uint2*)(in_bf + (size_t)(n0 + nl) * 64 + 2 * u2);
        float4 f = make_float4(bflo(u.x), bfhi(u.x), bflo(u.y), bfhi(u.y));
        *(float4*)(As + nl * 128 + 4 * u2) = f;
    }
    const int cg = t & 31;            // cols 4cg .. 4cg+3
    const int rg = (t >> 5) * 4;      // rows rg .. rg+3
    float4 bv = *(const float4*)(bias + 4 * cg);
    float acc[4][4];
#pragma unroll
    for (int i = 0; i < 4; ++i) {
        acc[i][0] = bv.x; acc[i][1] = bv.y; acc[i][2] = bv.z; acc[i][3] = bv.w;
    }
    for (int kc = 0; kc < 2; ++kc) {
        __syncthreads();
        for (int i = t; i < 64 * 32; i += 256) {
            int k = i >> 5, c4 = i & 31;
            ((float4*)Ws)[i] = *(const float4*)(W + (size_t)(kc * 64 + k) * 128 + c4 * 4);
        }
        __syncthreads();
        const float* Ab = As + kc * 64;
        for (int k = 0; k < 64; ++k) {
            float4 w = ((const float4*)Ws)[k * 32 + cg];
#pragma unroll
            for (int i = 0; i < 4; ++i) {
                float a = Ab[(rg + i) * 128 + k];
                acc[i][0] += a * w.x; acc[i][1] += a * w.y;
                acc[i][2] += a * w.z; acc[i][3] += a * w.w;
            }
        }
    }
#pragma unroll
    for (int i = 0; i < 4; ++i) {
        uint2 u = make_uint2(bfpack(acc[i][0], acc[i][1]), bfpack(acc[i][2], acc[i][3]));
        *(uint2*)(outp + (size_t)(n0 + rg + i) * 64 + 2 * cg) = u;
    }
}

// ---- edge scores in CSR position order (R9-proven per-(edge,head) version) ----
__global__ __launch_bounds__(256) void edge_scores_csr(
    const unsigned* __restrict__ q_bf, const unsigned* __restrict__ k_bf,
    const int* __restrict__ csrc, const int* __restrict__ cdst,
    const float* __restrict__ p4, float* __restrict__ s_out)
{
    int idx = blockIdx.x * 256 + threadIdx.x;
    if (idx >= EE * 4) return;
    int p = idx >> 2, hh = idx & 3;
    int src = csrc[p], dst = cdst[p];
    const uint4* qp = (const uint4*)(q_bf + (size_t)dst * 64 + hh * 16);
    const uint4* kp = (const uint4*)(k_bf + (size_t)src * 64 + hh * 16);
    float sum = 0.f;
#pragma unroll
    for (int i = 0; i < 4; ++i) {
        uint4 qa = qp[i], ka = kp[i];
        sum += bflo(qa.x) * bflo(ka.x) + bfhi(qa.x) * bfhi(ka.x);
        sum += bflo(qa.y) * bflo(ka.y) + bfhi(qa.y) * bfhi(ka.y);
        sum += bflo(qa.z) * bflo(ka.z) + bfhi(qa.z) * bfhi(ka.z);
        sum += bflo(qa.w) * bflo(ka.w) + bfhi(qa.w) * bfhi(ka.w);
    }
    s_out[(size_t)p * 4 + hh] = sum * p4[hh] * INV_SQRT_D;
}

// ---- CSR segment softmax (coalesced, zero indirection) ----
__global__ __launch_bounds__(256) void csr_softmax(
    float* __restrict__ s, const int* __restrict__ rp)
{
    const int dst = blockIdx.x * 4 + (threadIdx.x >> 6);
    const int lane = threadIdx.x & 63;
    const int sub = lane >> 2, hh = lane & 3;
    int beg[3], end[3];
#pragma unroll
    for (int r = 0; r < 3; ++r) {
        beg[r] = rp[r * SCAN_L + dst];
        end[r] = rp[r * SCAN_L + dst + 1];
    }
    float m = -INFINITY;
#pragma unroll
    for (int r = 0; r < 3; ++r)
        for (int p = beg[r] + sub; p < end[r]; p += 16)
            m = fmaxf(m, s[((size_t)r * EE + p) * 4 + hh]);
#pragma unroll
    for (int st = 4; st < 64; st <<= 1) m = fmaxf(m, __shfl_xor(m, st));
    float zz = 0.f;
#pragma unroll
    for (int r = 0; r < 3; ++r)
        for (int p = beg[r] + sub; p < end[r]; p += 16) {
            size_t off = ((size_t)r * EE + p) * 4 + hh;
            float ex = expf(s[off] - m);
            s[off] = ex;
            zz += ex;
        }
#pragma unroll
    for (int st = 4; st < 64; st <<= 1) zz += __shfl_xor(zz, st);
    float inv = 1.f / (zz + 1e-16f);
#pragma unroll
    for (int r = 0; r < 3; ++r)
        for (int p = beg[r] + sub; p < end[r]; p += 16)
            s[((size_t)r * EE + p) * 4 + hh] *= inv;
}

// ---- agg_reg: wave-per-dst register aggregation of TRANSFORMED vt planes.
// No LDS, no atomics; ~5 instrs/edge/lane; avg degree 1.5/relation so loops are
// short — rely on 8 blocks/CU occupancy + 2-wide unroll for latency hiding.
// NREL=2: relations ra (plane pA) then rb (plane pB). FIRST: write vs RMW-add As. ----
template<int NREL, int FIRST>
__global__ __launch_bounds__(256, 8) void agg_reg(
    const unsigned* __restrict__ pA, const unsigned* __restrict__ pB,
    const float* __restrict__ s, const int* __restrict__ rp,
    const int* __restrict__ csrc, int ra, int rb,
    unsigned* __restrict__ As_g)
{
    const int dst = blockIdx.x * 4 + (threadIdx.x >> 6);
    const int lane = threadIdx.x & 63;
    const int hh = lane >> 4;
    float a0 = 0.f, a1 = 0.f;
#pragma unroll
    for (int q = 0; q < NREL; ++q) {
        const unsigned* pl = q ? pB : pA;
        const int r = q ? rb : ra;
        const int beg = rp[r * SCAN_L + dst];
        const int end = rp[r * SCAN_L + dst + 1];
        int p = beg;
        for (; p + 1 < end; p += 2) {       // 2 independent gathers in flight
            int s0 = csrc[r * EE + p];
            float al0 = s[((size_t)r * EE + p) * 4 + hh];
            int s1 = csrc[r * EE + p + 1];
            float al1 = s[((size_t)r * EE + p + 1) * 4 + hh];
            unsigned v0 = pl[(size_t)s0 * 64 + lane];
            unsigned v1 = pl[(size_t)s1 * 64 + lane];
            a0 += al0 * bflo(v0) + al1 * bflo(v1);
            a1 += al0 * bfhi(v0) + al1 * bfhi(v1);
        }
        if (p < end) {
            int s0 = csrc[r * EE + p];
            float al0 = s[((size_t)r * EE + p) * 4 + hh];
            unsigned v0 = pl[(size_t)s0 * 64 + lane];
            a0 += al0 * bflo(v0);
            a1 += al0 * bfhi(v0);
        }
    }
    size_t off = (size_t)dst * 64 + lane;
    if (FIRST) {
        As_g[off] = bfpack(a0, a1);
    } else {
        unsigned old = As_g[off];
        As_g[off] = bfpack(bflo(old) + a0, bfhi(old) + a1);
    }
}

// ---- out_ln: gelu(As bf16) @ Wout + bout -> skip -> LayerNorm -> h (bf16). ----
__global__ __launch_bounds__(256) void out_ln(
    const unsigned* __restrict__ As_g, unsigned* __restrict__ h_bf,
    const float* __restrict__ Wout, const float* __restrict__ bout,
    const float* __restrict__ skipp, const float* __restrict__ lg,
    const float* __restrict__ lb)
{
    __shared__ float Asl[32 * 130];   // 16640 B (padded pitch 130)
    __shared__ float Ws[64 * 128];    // 32768 B
    const int t = threadIdx.x;
    const int n0 = blockIdx.x * 32;
    for (int i = t; i < 32 * 64; i += 256) {
        int row = i >> 6, j = i & 63;
        unsigned u = As_g[(size_t)(n0 + row) * 64 + j];
        Asl[row * 130 + 2 * j]     = gelu_exact(bflo(u));
        Asl[row * 130 + 2 * j + 1] = gelu_exact(bfhi(u));
    }
    const int cg = t & 31;            // cols 4cg..4cg+3
    const int rg = (t >> 5) * 4;      // rows rg..rg+3
    float4 bv = *(const float4*)(bout + 4 * cg);
    float acc[4][4];
#pragma unroll
    for (int i = 0; i < 4; ++i) {
        acc[i][0] = bv.x; acc[i][1] = bv.y; acc[i][2] = bv.z; acc[i][3] = bv.w;
    }
    for (int kc = 0; kc < 2; ++kc) {
        __syncthreads();
        for (int i = t; i < 64 * 32; i += 256) {
            int k = i >> 5, c4 = i & 31;
            ((float4*)Ws)[i] = *(const float4*)(Wout + (size_t)(kc * 64 + k) * 128 + c4 * 4);
        }
        __syncthreads();
        for (int k = 0; k < 64; ++k) {
            float4 w = ((const float4*)Ws)[k * 32 + cg];
#pragma unroll
            for (int i = 0; i < 4; ++i) {
                float a = Asl[(rg + i) * 130 + kc * 64 + k];
                acc[i][0] += a * w.x; acc[i][1] += a * w.y;
                acc[i][2] += a * w.z; acc[i][3] += a * w.w;
            }
        }
    }
    const float alpha = 1.f / (1.f + expf(-skipp[0]));
    const float om = 1.f - alpha;
    float4 g4 = *(const float4*)(lg + 4 * cg);
    float4 b4 = *(const float4*)(lb + 4 * cg);
#pragma unroll
    for (int i = 0; i < 4; ++i) {
        const size_t n = (size_t)(n0 + rg + i);
        uint2 hu = *(const uint2*)(h_bf + n * 64 + 2 * cg);
        float o0 = alpha * acc[i][0] + om * bflo(hu.x);
        float o1 = alpha * acc[i][1] + om * bfhi(hu.x);
        float o2 = alpha * acc[i][2] + om * bflo(hu.y);
        float o3 = alpha * acc[i][3] + om * bfhi(hu.y);
        float sm = o0 + o1 + o2 + o3;
#pragma unroll
        for (int m = 1; m < 32; m <<= 1) sm += __shfl_xor(sm, m);
        float mu = sm * (1.f / 128.f);
        float d0 = o0 - mu, d1 = o1 - mu, d2 = o2 - mu, d3 = o3 - mu;
        float sq = d0 * d0 + d1 * d1 + d2 * d2 + d3 * d3;
#pragma unroll
        for (int m = 1; m < 32; m <<= 1) sq += __shfl_xor(sq, m);
        float rs = rsqrtf(sq * (1.f / 128.f) + 1e-5f);
        uint2 o = make_uint2(
            bfpack(d0 * rs * g4.x + b4.x, d1 * rs * g4.y + b4.y),
            bfpack(d2 * rs * g4.z + b4.z, d3 * rs * g4.w + b4.w));
        *(uint2*)(h_bf + n * 64 + 2 * cg) = o;
    }
}

// ---- parallel masked mean-pool partials (batch sorted -> run-flush; h bf16) ----
__global__ __launch_bounds__(256) void pool_partial(
    const unsigned* __restrict__ h_bf, const float* __restrict__ x,
    const int* __restrict__ batch, float* __restrict__ psum, float* __restrict__ pcnt)
{
    const int c2 = threadIdx.x & 63;          // col pair 2c2, 2c2+1
    const int n0 = blockIdx.x * 64 + (threadIdx.x >> 6) * 16;
    int g = batch[n0];
    float sw0 = 0.f, sw1 = 0.f, sn0 = 0.f, sn1 = 0.f, cw = 0.f, cn = 0.f;
    for (int i = 0; i < 16; ++i) {
        int n = n0 + i;
        int gn = batch[n];
        if (gn != g) {
            atomicAdd(&psum[g * 256 + 2 * c2], sw0);
            atomicAdd(&psum[g * 256 + 2 * c2 + 1], sw1);
            atomicAdd(&psum[g * 256 + 128 + 2 * c2], sn0);
            atomicAdd(&psum[g * 256 + 128 + 2 * c2 + 1], sn1);
            if (c2 == 0) { atomicAdd(&pcnt[g * 2], cw); atomicAdd(&pcnt[g * 2 + 1], cn); }
            sw0 = sw1 = sn0 = sn1 = cw = cn = 0.f;
            g = gn;
        }
        float w = (x[(size_t)n * 5 + 1] > 0.f) ? 1.f : 0.f;
        unsigned u = h_bf[(size_t)n * 64 + c2];
        float h0 = bflo(u), h1 = bfhi(u);
        sw0 += w * h0; sw1 += w * h1;
        sn0 += (1.f - w) * h0; sn1 += (1.f - w) * h1;
        cw += w; cn += 1.f - w;
    }
    atomicAdd(&psum[g * 256 + 2 * c2], sw0);
    atomicAdd(&psum[g * 256 + 2 * c2 + 1], sw1);
    atomicAdd(&psum[g * 256 + 128 + 2 * c2], sn0);
    atomicAdd(&psum[g * 256 + 128 + 2 * c2 + 1], sn1);
    if (c2 == 0) { atomicAdd(&pcnt[g * 2], cw); atomicAdd(&pcnt[g * 2 + 1], cn); }
}

// ---------------- MLP head (pool finalize fused) ----------------
__global__ __launch_bounds__(256) void head_kernel(
    const float* __restrict__ psum, const float* __restrict__ pcnt,
    const float* __restrict__ task,
    const float* __restrict__ Wtf, const float* __restrict__ btf,
    const float* __restrict__ Wc1, const float* __restrict__ bc1,
    const float* __restrict__ Wc2, const float* __restrict__ bc2,
    float* __restrict__ out)
{
    __shared__ float in_s[640];
    __shared__ float ge_s[256];
    __shared__ float hc_s[64];
    const int b = blockIdx.x, t = threadIdx.x;
    if (t < 256) {
        float cnt = pcnt[b * 2 + (t >> 7)];
        float sv = psum[b * 256 + t];
        in_s[t] = (cnt > 0.f) ? sv / fmaxf(cnt, 1.f) : 0.f;
    }
    for (int i = t; i < 384; i += 256) in_s[256 + i] = task[b * 384 + i];
    __syncthreads();
    float acc = btf[t];
    for (int i = 0; i < 640; ++i) acc += in_s[i] * Wtf[i * 256 + t];
    ge_s[t] = fmaxf(acc, 0.f);
    __syncthreads();
    if (t < 64) {
        float a2 = bc1[t];
        for (int i = 0; i < 256; ++i) a2 += ge_s[i] * Wc1[i * 64 + t];
        hc_s[t] = fmaxf(a2, 0.f);
    }
    __syncthreads();
    if (t < 64) {
        float v = hc_s[t] * Wc2[t];
#pragma unroll
        for (int off = 32; off >= 1; off >>= 1) v += __shfl_down(v, off);
        if (t == 0) out[b] = v + bc2[0];
    }
}

__global__ __launch_bounds__(256) void zero_kernel(float4* __restrict__ p, int count4)
{
    int i = blockIdx.x * 256 + threadIdx.x;
    if (i < count4) p[i] = make_float4(0.f, 0.f, 0.f, 0.f);
}

extern "C" void kernel_launch(void* const* d_in, const int* in_sizes, int n_in,
                              void* d_out, int out_size, void* d_ws, size_t ws_size,
                              hipStream_t stream)
{
    const float* x      = (const float*)d_in[0];
    const int*   ast    = (const int*)d_in[1];
    const int*   batch  = (const int*)d_in[2];
    const int*   ei[3]  = {(const int*)d_in[3], (const int*)d_in[4], (const int*)d_in[5]};
    const float* task   = (const float*)d_in[6];
    const float* emb    = (const float*)d_in[7];
    const float* Win    = (const float*)d_in[8];
    const float* bin_   = (const float*)d_in[9];
    const float* Wkqv   = (const float*)d_in[10];
    const float* bkqv   = (const float*)d_in[11];
    const float* Wk_rel = (const float*)d_in[12];
    const float* Wv_rel = (const float*)d_in[13];
    const float* p_rel  = (const float*)d_in[14];
    const float* Wout   = (const float*)d_in[15];
    const float* bout   = (const float*)d_in[16];
    const float* skip   = (const float*)d_in[17];
    const float* ln_g   = (const float*)d_in[18];
    const float* ln_b   = (const float*)d_in[19];
    const float* Wtf    = (const float*)d_in[20];
    const float* btf    = (const float*)d_in[21];
    const float* Wc1    = (const float*)d_in[22];
    const float* bc1    = (const float*)d_in[23];
    const float* Wc2    = (const float*)d_in[24];
    const float* bc2    = (const float*)d_in[25];
    float* out = (float*)d_out;
    float* ws  = (float*)d_ws;

    unsigned* hB   = (unsigned*)(ws + OFF_HB);
    unsigned* P0   = (unsigned*)(ws + OFF_P0);   // q -> vt_0 -> vt_2
    unsigned* P1   = (unsigned*)(ws + OFF_P1);   // kt_r -> vt_1
    unsigned* AS   = (unsigned*)(ws + OFF_AS);
    float*    sbuf = ws + OFF_S;
    int*      rp   = (int*)(ws + OFF_RP);
    int*      csrc = (int*)(ws + OFF_CSRC);
    int*      cdst = (int*)(ws + OFF_CDST);
    int*      fill = (int*)(ws + OFF_P0);        // aliases P0 during CSR build only
    float*    Wf   = ws + OFF_WF;
    float*    bf   = ws + OFF_BF;
    int*      bs   = (int*)(ws + OFF_BS);
    float*    psum = ws + OFF_POOL;
    float*    pcnt = psum + (size_t)BB * 256;

    fold_weights<<<14, 256, 0, stream>>>(Wkqv, bkqv, Wk_rel, Wv_rel, Wf, bf);
    input_proj<<<NN / 16, 256, 0, stream>>>(x, ast, emb, Win, bin_, hB);

    zero_kernel<<<(600016 / 4 + 255) / 256, 256, 0, stream>>>((float4*)rp, 600016 / 4);
    zero_kernel<<<(600000 / 4 + 255) / 256, 256, 0, stream>>>((float4*)fill, 600000 / 4);
    csr_hist<<<(3 * EE + 255) / 256, 256, 0, stream>>>(ei[0], ei[1], ei[2], rp);
    scan1<<<dim3(SCAN_NB, 3), 256, 0, stream>>>(rp, bs);
    scan2<<<3, 128, 0, stream>>>(bs);
    scan3<<<dim3(SCAN_NB, 3), 256, 0, stream>>>(rp, bs);
    csr_scatter<<<(3 * EE + 255) / 256, 256, 0, stream>>>(
        ei[0], ei[1], ei[2], rp, fill, csrc, cdst);

    for (int l = 0; l < 2; ++l) {
        const size_t ls = (size_t)l * 7;   // slots: 0=q, 1..3=kt_r, 4..6=vt_r
        gemm_bf<<<NN / 32, 256, 0, stream>>>(hB, Wf + ls * 16384, bf + ls * 128, P0);
        for (int r = 0; r < 3; ++r) {
            gemm_bf<<<NN / 32, 256, 0, stream>>>(
                hB, Wf + (ls + 1 + r) * 16384, bf + (ls + 1 + r) * 128, P1);
            edge_scores_csr<<<(EE * 4 + 255) / 256, 256, 0, stream>>>(
                P0, P1, csrc + (size_t)r * EE, cdst + (size_t)r * EE,
                p_rel + (size_t)(l * 3 + r) * 4, sbuf + (size_t)r * EE * 4);
        }
        csr_softmax<<<NN / 4, 256, 0, stream>>>(sbuf, rp);
        // phase B: q dead -> P0 = vt_0; kt dead -> P1 = vt_1; then P0 = vt_2
        gemm_bf<<<NN / 32, 256, 0, stream>>>(hB, Wf + (ls + 4) * 16384, bf + (ls + 4) * 128, P0);
        gemm_bf<<<NN / 32, 256, 0, stream>>>(hB, Wf + (ls + 5) * 16384, bf + (ls + 5) * 128, P1);
        agg_reg<2, 1><<<NN / 4, 256, 0, stream>>>(P0, P1, sbuf, rp, csrc, 0, 1, AS);
        gemm_bf<<<NN / 32, 256, 0, stream>>>(hB, Wf + (ls + 6) * 16384, bf + (ls + 6) * 128, P0);
        agg_reg<1, 0><<<NN / 4, 256, 0, stream>>>(P0, P0, sbuf, rp, csrc, 2, 2, AS);
        out_ln<<<NN / 32, 256, 0, stream>>>(
            AS, hB, Wout + (size_t)l * 16384, bout + (size_t)l * 128,
            skip + l, ln_g + (size_t)l * 128, ln_b + (size_t)l * 128);
    }

    zero_kernel<<<(16512 / 4 + 255) / 256, 256, 0, stream>>>((float4*)psum, 16512 / 4);
    pool_partial<<<NN / 64, 256, 0, stream>>>(hB, x, batch, psum, pcnt);
    head_kernel<<<BB, 256, 0, stream>>>(psum, pcnt, task, Wtf, btf, Wc1, bc1, Wc2, bc2, out);
}

// Round 12
// 1666.658 us; speedup vs baseline: 2.2114x; 1.6002x over previous
//
#include <hip/hip_runtime.h>
#include <math.h>

// Problem constants (match reference)
#define NN 200000
#define EE 300000
#define BB 64
#define INV_SQRT_D 0.17677669529663687f

// ---- workspace layout in 4-byte words. Total ≈ 57.58M words = 230.3 MB.
// ws budget is ~256MB-class (252 passed, 329 faulted) -> stay <= 252 MB.
#define OFF_HB   ((size_t)0)                    // [N][64] uint (bf16x2) node features
#define OFF_P0   ((size_t)12800000)             // [N][64] uint: q, then vt_0, then vt_2
#define OFF_P1   ((size_t)25600000)             // [N][64] uint: kt_r, then vt_1
#define OFF_AS   ((size_t)38400000)             // [N][64] uint: As accumulator (bf16)
#define OFF_S    ((size_t)51200000)             // [3][E][4] f32 scores -> alpha (CSR order)
#define OFF_RP   ((size_t)54800000)             // [3][N+1] int rowptr (padded 600016)
#define OFF_CSRC ((size_t)55400016)             // [3][E] int src per CSR position
#define OFF_CDST ((size_t)56300016)             // [3][E] int dst per CSR position
#define OFF_WF   ((size_t)57200016)             // 14 x [128][128] f32 folded weights
#define OFF_BF   ((size_t)57429392)             // 14 x [128] f32 folded bias
#define OFF_BS   ((size_t)57431184)             // scan block sums 3*128 int
#define OFF_POOL ((size_t)57431568)             // psum [B][256] + pcnt [B][2] (16512)
#define OFF_WT   ((size_t)57448080)             // 16 x [128][64] uint packed W^T (14 Wf + 2 Wout)

#define SCAN_L   (NN + 1)
#define SCAN_E   8
#define SCAN_EPB (256 * SCAN_E)                          // 2048
#define SCAN_NB  ((SCAN_L + SCAN_EPB - 1) / SCAN_EPB)    // 98

typedef __attribute__((ext_vector_type(8))) short bf16x8;
typedef __attribute__((ext_vector_type(4))) float f32x4;

__device__ __forceinline__ float gelu_exact(float v) {
    return 0.5f * v * (1.0f + erff(v * 0.70710678118654752f));
}
__device__ __forceinline__ float bflo(unsigned u) { return __uint_as_float(u << 16); }
__device__ __forceinline__ float bfhi(unsigned u) { return __uint_as_float(u & 0xffff0000u); }
__device__ __forceinline__ unsigned bfpack(float a, float b) {
    unsigned ua = __float_as_uint(a); ua += 0x7fffu + ((ua >> 16) & 1u);
    unsigned ub = __float_as_uint(b); ub += 0x7fffu + ((ub >> 16) & 1u);
    return (ua >> 16) | (ub & 0xffff0000u);
}

// ---- fold weights. 14 slots: per layer l: [l*7+0]=q copy, [l*7+1+r]=k@Wk_rel[r],
//      [l*7+4+r]=v@Wv_rel[r].  kqv split order is k|q|v (cols 0/128/256).
__global__ __launch_bounds__(256) void fold_weights(
    const float* __restrict__ Wkqv, const float* __restrict__ bkqv,
    const float* __restrict__ Wk_rel, const float* __restrict__ Wv_rel,
    float* __restrict__ Wf, float* __restrict__ bf)
{
    __shared__ float Wr[4096];
    const int b = blockIdx.x, t = threadIdx.x;
    const int l = b / 7, s = b % 7;
    const float* Wq = Wkqv + (size_t)l * 49152;   // [128][384]
    if (s == 0) {
        for (int i = t; i < 16384; i += 256) {
            int kk = i >> 7, c = i & 127;
            Wf[(size_t)b * 16384 + i] = Wq[kk * 384 + 128 + c];
        }
        if (t < 128) bf[b * 128 + t] = bkqv[l * 384 + 128 + t];
    } else {
        const int side = (s - 1) / 3, r = (s - 1) % 3;
        const int off = side ? 256 : 0;
        const float* Wrel = (side ? Wv_rel : Wk_rel) + (size_t)(l * 3 + r) * 4096;
        for (int i = t; i < 4096; i += 256) Wr[i] = Wrel[i];
        __syncthreads();
        for (int i = t; i < 16384; i += 256) {
            int kk = i >> 7, c = i & 127, hh = c >> 5, f = c & 31;
            const float* wrow = Wq + kk * 384 + off + hh * 32;
            const float* wr = Wr + hh * 1024 + f;
            float sum = 0.f;
#pragma unroll
            for (int d = 0; d < 32; ++d) sum += wrow[d] * wr[d * 32];
            Wf[(size_t)b * 16384 + i] = sum;
        }
        if (t < 128) {
            int hh = t >> 5, f = t & 31;
            float sum = 0.f;
#pragma unroll
            for (int d = 0; d < 32; ++d)
                sum += bkqv[l * 384 + off + hh * 32 + d] * Wr[hh * 1024 + d * 32 + f];
            bf[b * 128 + t] = sum;
        }
    }
}

// ---- pack W -> bf16x2-packed W^T: WT[slot][c][w] = (W[2w][c], W[2w+1][c]) ----
__global__ __launch_bounds__(256) void pack_wt(
    const float* __restrict__ W, unsigned* __restrict__ WT)
{
    const int slot = blockIdx.x, t = threadIdx.x;
    const float* Ws = W + (size_t)slot * 16384;
    unsigned* WTs = WT + (size_t)slot * 8192;
    for (int i = t; i < 8192; i += 256) {
        int c = i >> 6, w = i & 63;
        WTs[i] = bfpack(Ws[(size_t)(2 * w) * 128 + c], Ws[(size_t)(2 * w + 1) * 128 + c]);
    }
}

// ---------------- input projection: h_bf = bf16([emb[ast], x] @ Win + bin) ----------------
__global__ __launch_bounds__(256) void input_proj(
    const float* __restrict__ x, const int* __restrict__ ast,
    const float* __restrict__ emb, const float* __restrict__ Win,
    const float* __restrict__ bin_, unsigned* __restrict__ h_bf)
{
    __shared__ float Ws[69 * 128];
    __shared__ float As[16 * 70];
    const int t = threadIdx.x;
    const int n0 = blockIdx.x * 16;
    for (int i = t; i < 69 * 128; i += 256) Ws[i] = Win[i];
    for (int i = t; i < 16 * 69; i += 256) {
        int nl = i / 69, kk = i - nl * 69;
        int n = n0 + nl;
        float v = (kk < 64) ? emb[ast[n] * 64 + kk] : x[n * 5 + (kk - 64)];
        As[nl * 70 + kk] = v;
    }
    __syncthreads();
    const int c2 = t & 63;            // col pair 2c2, 2c2+1
    const int nh = (t >> 6) * 4;      // 4 rows
    float acc0[4], acc1[4];
    float b0 = bin_[2 * c2], b1 = bin_[2 * c2 + 1];
#pragma unroll
    for (int j = 0; j < 4; ++j) { acc0[j] = b0; acc1[j] = b1; }
    for (int k = 0; k < 69; ++k) {
        float w0 = Ws[k * 128 + 2 * c2];
        float w1 = Ws[k * 128 + 2 * c2 + 1];
#pragma unroll
        for (int j = 0; j < 4; ++j) {
            float a = As[(nh + j) * 70 + k];
            acc0[j] += a * w0;
            acc1[j] += a * w1;
        }
    }
#pragma unroll
    for (int j = 0; j < 4; ++j)
        h_bf[(size_t)(n0 + nh + j) * 64 + c2] = bfpack(acc0[j], acc1[j]);
}

// ---- CSR build: histogram -> scan -> scatter ----
__global__ __launch_bounds__(256) void csr_hist(
    const int* __restrict__ ei0, const int* __restrict__ ei1, const int* __restrict__ ei2,
    int* __restrict__ rp)
{
    int idx = blockIdx.x * 256 + threadIdx.x;
    if (idx >= 3 * EE) return;
    int r = idx / EE, e = idx - r * EE;
    const int* ei = (r == 0) ? ei0 : ((r == 1) ? ei1 : ei2);
    atomicAdd(&rp[r * SCAN_L + ei[EE + e] + 1], 1);
}

__global__ __launch_bounds__(256) void scan1(int* __restrict__ rp, int* __restrict__ bs)
{
    __shared__ int ts[256];
    const int r = blockIdx.y;
    int* a = rp + (size_t)r * SCAN_L;
    const int base = blockIdx.x * SCAN_EPB + threadIdx.x * SCAN_E;
    int v[SCAN_E];
    int tot = 0;
#pragma unroll
    for (int j = 0; j < SCAN_E; ++j) {
        int idx = base + j;
        v[j] = (idx < SCAN_L) ? a[idx] : 0;
        tot += v[j];
    }
    ts[threadIdx.x] = tot;
    __syncthreads();
    for (int st = 1; st < 256; st <<= 1) {
        int add = (threadIdx.x >= st) ? ts[threadIdx.x - st] : 0;
        __syncthreads();
        ts[threadIdx.x] += add;
        __syncthreads();
    }
    int run = ts[threadIdx.x] - tot;
#pragma unroll
    for (int j = 0; j < SCAN_E; ++j) {
        run += v[j];
        int idx = base + j;
        if (idx < SCAN_L) a[idx] = run;
    }
    if (threadIdx.x == 255) bs[r * 128 + blockIdx.x] = ts[255];
}

__global__ __launch_bounds__(128) void scan2(int* __restrict__ bs)
{
    __shared__ int ts[128];
    const int r = blockIdx.x, t = threadIdx.x;
    int v = (t < SCAN_NB) ? bs[r * 128 + t] : 0;
    ts[t] = v;
    __syncthreads();
    for (int st = 1; st < 128; st <<= 1) {
        int add = (t >= st) ? ts[t - st] : 0;
        __syncthreads();
        ts[t] += add;
        __syncthreads();
    }
    bs[r * 128 + t] = ts[t];
}

__global__ __launch_bounds__(256) void scan3(int* __restrict__ rp, const int* __restrict__ bs)
{
    const int r = blockIdx.y;
    if (blockIdx.x == 0) return;
    const int off = bs[r * 128 + blockIdx.x - 1];
    const int base = blockIdx.x * SCAN_EPB + threadIdx.x * SCAN_E;
    int* a = rp + (size_t)r * SCAN_L;
#pragma unroll
    for (int j = 0; j < SCAN_E; ++j) {
        int idx = base + j;
        if (idx < SCAN_L) a[idx] += off;
    }
}

__global__ __launch_bounds__(256) void csr_scatter(
    const int* __restrict__ ei0, const int* __restrict__ ei1, const int* __restrict__ ei2,
    const int* __restrict__ rp, int* __restrict__ fill,
    int* __restrict__ csrc, int* __restrict__ cdst)
{
    int idx = blockIdx.x * 256 + threadIdx.x;
    if (idx >= 3 * EE) return;
    int r = idx / EE, e = idx - r * EE;
    const int* ei = (r == 0) ? ei0 : ((r == 1) ? ei1 : ei2);
    int src = ei[e], dst = ei[EE + e];
    int pos = rp[r * SCAN_L + dst] + atomicAdd(&fill[r * NN + dst], 1);
    csrc[r * EE + pos] = src;
    cdst[r * EE + pos] = dst;
}

// ---- MFMA GEMM: out[n0..n0+31][0:128] = in_bf @ W + bias, all bf16 planes.
// A-frag: A[m=lane&15][k=quad*8+j]; B-frag: B[n=lane&15][k=quad*8+j] (from W^T);
// C/D: row=quad*4+reg, col=lane&15  (per cdna_hip_programming.md §3, HW-verified).
// LDS pitch 68 words -> conflict-free ds_read_b128 fragment loads.
__global__ __launch_bounds__(256) void gemm_mfma(
    const unsigned* __restrict__ in_bf, const unsigned* __restrict__ WT,
    const float* __restrict__ bias, unsigned* __restrict__ outp)
{
    __shared__ unsigned Asm[32 * 68];    // 8704 B
    __shared__ unsigned Bsm[128 * 68];   // 34816 B
    const int t = threadIdx.x;
    const int n0 = blockIdx.x * 32;
    for (int i = t; i < 32 * 16; i += 256) {
        int row = i >> 4, q4 = i & 15;
        uint4 v = *(const uint4*)(in_bf + (size_t)(n0 + row) * 64 + q4 * 4);
        *(uint4*)&Asm[row * 68 + q4 * 4] = v;
    }
    for (int i = t; i < 128 * 16; i += 256) {
        int row = i >> 4, q4 = i & 15;
        uint4 v = *(const uint4*)(WT + (size_t)row * 64 + q4 * 4);
        *(uint4*)&Bsm[row * 68 + q4 * 4] = v;
    }
    __syncthreads();
    const int w = t >> 6, lane = t & 63;
    const int m = lane & 15, quad = lane >> 4;
    const int tc0 = 2 * w;               // this wave's col-tiles: tc0, tc0+1
    f32x4 acc00 = {0.f, 0.f, 0.f, 0.f}, acc01 = acc00, acc10 = acc00, acc11 = acc00;
#pragma unroll
    for (int kc = 0; kc < 4; ++kc) {
        const int koff = kc * 16 + quad * 4;
        bf16x8 a0 = *(const bf16x8*)&Asm[m * 68 + koff];
        bf16x8 a1 = *(const bf16x8*)&Asm[(16 + m) * 68 + koff];
        bf16x8 b0 = *(const bf16x8*)&Bsm[(tc0 * 16 + m) * 68 + koff];
        bf16x8 b1 = *(const bf16x8*)&Bsm[((tc0 + 1) * 16 + m) * 68 + koff];
        acc00 = __builtin_amdgcn_mfma_f32_16x16x32_bf16(a0, b0, acc00, 0, 0, 0);
        acc01 = __builtin_amdgcn_mfma_f32_16x16x32_bf16(a0, b1, acc01, 0, 0, 0);
        acc10 = __builtin_amdgcn_mfma_f32_16x16x32_bf16(a1, b0, acc10, 0, 0, 0);
        acc11 = __builtin_amdgcn_mfma_f32_16x16x32_bf16(a1, b1, acc11, 0, 0, 0);
    }
    __syncthreads();
    float* Cs = (float*)Bsm;             // [32][132] f32 (16896 B, fits)
#pragma unroll
    for (int r = 0; r < 4; ++r) {
        Cs[(quad * 4 + r) * 132 + tc0 * 16 + m]            = acc00[r];
        Cs[(quad * 4 + r) * 132 + (tc0 + 1) * 16 + m]      = acc01[r];
        Cs[(16 + quad * 4 + r) * 132 + tc0 * 16 + m]       = acc10[r];
        Cs[(16 + quad * 4 + r) * 132 + (tc0 + 1) * 16 + m] = acc11[r];
    }
    __syncthreads();
    for (int i = t; i < 32 * 64; i += 256) {
        int row = i >> 6, c2 = i & 63;
        float c0 = Cs[row * 132 + 2 * c2]     + bias[2 * c2];
        float c1 = Cs[row * 132 + 2 * c2 + 1] + bias[2 * c2 + 1];
        outp[(size_t)(n0 + row) * 64 + c2] = bfpack(c0, c1);
    }
}

// ---- edge scores in CSR position order ----
__global__ __launch_bounds__(256) void edge_scores_csr(
    const unsigned* __restrict__ q_bf, const unsigned* __restrict__ k_bf,
    const int* __restrict__ csrc, const int* __restrict__ cdst,
    const float* __restrict__ p4, float* __restrict__ s_out)
{
    int idx = blockIdx.x * 256 + threadIdx.x;
    if (idx >= EE * 4) return;
    int p = idx >> 2, hh = idx & 3;
    int src = csrc[p], dst = cdst[p];
    const uint4* qp = (const uint4*)(q_bf + (size_t)dst * 64 + hh * 16);
    const uint4* kp = (const uint4*)(k_bf + (size_t)src * 64 + hh * 16);
    float sum = 0.f;
#pragma unroll
    for (int i = 0; i < 4; ++i) {
        uint4 qa = qp[i], ka = kp[i];
        sum += bflo(qa.x) * bflo(ka.x) + bfhi(qa.x) * bfhi(ka.x);
        sum += bflo(qa.y) * bflo(ka.y) + bfhi(qa.y) * bfhi(ka.y);
        sum += bflo(qa.z) * bflo(ka.z) + bfhi(qa.z) * bfhi(ka.z);
        sum += bflo(qa.w) * bflo(ka.w) + bfhi(qa.w) * bfhi(ka.w);
    }
    s_out[(size_t)p * 4 + hh] = sum * p4[hh] * INV_SQRT_D;
}

// ---- CSR segment softmax (coalesced, zero indirection) ----
__global__ __launch_bounds__(256) void csr_softmax(
    float* __restrict__ s, const int* __restrict__ rp)
{
    const int dst = blockIdx.x * 4 + (threadIdx.x >> 6);
    const int lane = threadIdx.x & 63;
    const int sub = lane >> 2, hh = lane & 3;
    int beg[3], end[3];
#pragma unroll
    for (int r = 0; r < 3; ++r) {
        beg[r] = rp[r * SCAN_L + dst];
        end[r] = rp[r * SCAN_L + dst + 1];
    }
    float m = -INFINITY;
#pragma unroll
    for (int r = 0; r < 3; ++r)
        for (int p = beg[r] + sub; p < end[r]; p += 16)
            m = fmaxf(m, s[((size_t)r * EE + p) * 4 + hh]);
#pragma unroll
    for (int st = 4; st < 64; st <<= 1) m = fmaxf(m, __shfl_xor(m, st));
    float zz = 0.f;
#pragma unroll
    for (int r = 0; r < 3; ++r)
        for (int p = beg[r] + sub; p < end[r]; p += 16) {
            size_t off = ((size_t)r * EE + p) * 4 + hh;
            float ex = expf(s[off] - m);
            s[off] = ex;
            zz += ex;
        }
#pragma unroll
    for (int st = 4; st < 64; st <<= 1) zz += __shfl_xor(zz, st);
    float inv = 1.f / (zz + 1e-16f);
#pragma unroll
    for (int r = 0; r < 3; ++r)
        for (int p = beg[r] + sub; p < end[r]; p += 16)
            s[((size_t)r * EE + p) * 4 + hh] *= inv;
}

// ---- agg_reg: wave-per-dst register aggregation of TRANSFORMED vt planes. ----
template<int NREL, int FIRST>
__global__ __launch_bounds__(256, 8) void agg_reg(
    const unsigned* __restrict__ pA, const unsigned* __restrict__ pB,
    const float* __restrict__ s, const int* __restrict__ rp,
    const int* __restrict__ csrc, int ra, int rb,
    unsigned* __restrict__ As_g)
{
    const int dst = blockIdx.x * 4 + (threadIdx.x >> 6);
    const int lane = threadIdx.x & 63;
    const int hh = lane >> 4;
    float a0 = 0.f, a1 = 0.f;
#pragma unroll
    for (int q = 0; q < NREL; ++q) {
        const unsigned* pl = q ? pB : pA;
        const int r = q ? rb : ra;
        const int beg = rp[r * SCAN_L + dst];
        const int end = rp[r * SCAN_L + dst + 1];
        int p = beg;
        for (; p + 1 < end; p += 2) {       // 2 independent gathers in flight
            int s0 = csrc[r * EE + p];
            float al0 = s[((size_t)r * EE + p) * 4 + hh];
            int s1 = csrc[r * EE + p + 1];
            float al1 = s[((size_t)r * EE + p + 1) * 4 + hh];
            unsigned v0 = pl[(size_t)s0 * 64 + lane];
            unsigned v1 = pl[(size_t)s1 * 64 + lane];
            a0 += al0 * bflo(v0) + al1 * bflo(v1);
            a1 += al0 * bfhi(v0) + al1 * bfhi(v1);
        }
        if (p < end) {
            int s0 = csrc[r * EE + p];
            float al0 = s[((size_t)r * EE + p) * 4 + hh];
            unsigned v0 = pl[(size_t)s0 * 64 + lane];
            a0 += al0 * bflo(v0);
            a1 += al0 * bfhi(v0);
        }
    }
    size_t off = (size_t)dst * 64 + lane;
    if (FIRST) {
        As_g[off] = bfpack(a0, a1);
    } else {
        unsigned old = As_g[off];
        As_g[off] = bfpack(bflo(old) + a0, bfhi(old) + a1);
    }
}

// ---- out_ln (MFMA core): gelu(As) @ Wout + bout -> skip -> LayerNorm -> h (bf16) ----
__global__ __launch_bounds__(256) void out_ln(
    const unsigned* __restrict__ As_g, unsigned* __restrict__ h_bf,
    const unsigned* __restrict__ WT, const float* __restrict__ bout,
    const float* __restrict__ skipp, const float* __restrict__ lg,
    const float* __restrict__ lb)
{
    __shared__ unsigned Asm[32 * 68];    // 8704 B (gelu'd A, bf16)
    __shared__ unsigned Bsm[128 * 68];   // 34816 B (WoutT), reused as C f32
    const int t = threadIdx.x;
    const int n0 = blockIdx.x * 32;
    for (int i = t; i < 32 * 64; i += 256) {
        int row = i >> 6, c2 = i & 63;
        unsigned u = As_g[(size_t)(n0 + row) * 64 + c2];
        Asm[row * 68 + c2] = bfpack(gelu_exact(bflo(u)), gelu_exact(bfhi(u)));
    }
    for (int i = t; i < 128 * 16; i += 256) {
        int row = i >> 4, q4 = i & 15;
        uint4 v = *(const uint4*)(WT + (size_t)row * 64 + q4 * 4);
        *(uint4*)&Bsm[row * 68 + q4 * 4] = v;
    }
    __syncthreads();
    const int w = t >> 6, lane = t & 63;
    const int m = lane & 15, quad = lane >> 4;
    const int tc0 = 2 * w;
    f32x4 acc00 = {0.f, 0.f, 0.f, 0.f}, acc01 = acc00, acc10 = acc00, acc11 = acc00;
#pragma unroll
    for (int kc = 0; kc < 4; ++kc) {
        const int koff = kc * 16 + quad * 4;
        bf16x8 a0 = *(const bf16x8*)&Asm[m * 68 + koff];
        bf16x8 a1 = *(const bf16x8*)&Asm[(16 + m) * 68 + koff];
        bf16x8 b0 = *(const bf16x8*)&Bsm[(tc0 * 16 + m) * 68 + koff];
        bf16x8 b1 = *(const bf16x8*)&Bsm[((tc0 + 1) * 16 + m) * 68 + koff];
        acc00 = __builtin_amdgcn_mfma_f32_16x16x32_bf16(a0, b0, acc00, 0, 0, 0);
        acc01 = __builtin_amdgcn_mfma_f32_16x16x32_bf16(a0, b1, acc01, 0, 0, 0);
        acc10 = __builtin_amdgcn_mfma_f32_16x16x32_bf16(a1, b0, acc10, 0, 0, 0);
        acc11 = __builtin_amdgcn_mfma_f32_16x16x32_bf16(a1, b1, acc11, 0, 0, 0);
    }
    __syncthreads();
    float* Cs = (float*)Bsm;             // [32][132] f32
#pragma unroll
    for (int r = 0; r < 4; ++r) {
        Cs[(quad * 4 + r) * 132 + tc0 * 16 + m]            = acc00[r];
        Cs[(quad * 4 + r) * 132 + (tc0 + 1) * 16 + m]      = acc01[r];
        Cs[(16 + quad * 4 + r) * 132 + tc0 * 16 + m]       = acc10[r];
        Cs[(16 + quad * 4 + r) * 132 + (tc0 + 1) * 16 + m] = acc11[r];
    }
    __syncthreads();
    // skip + LayerNorm epilogue (32 lanes cover a row's 128 cols, 4 each)
    const int cg = t & 31;            // cols 4cg..4cg+3
    const int rg = (t >> 5) * 4;      // rows rg..rg+3
    float4 bv = *(const float4*)(bout + 4 * cg);
    const float alpha = 1.f / (1.f + expf(-skipp[0]));
    const float om = 1.f - alpha;
    float4 g4 = *(const float4*)(lg + 4 * cg);
    float4 b4 = *(const float4*)(lb + 4 * cg);
#pragma unroll
    for (int i = 0; i < 4; ++i) {
        const size_t n = (size_t)(n0 + rg + i);
        float4 cc = *(const float4*)(Cs + (rg + i) * 132 + 4 * cg);
        uint2 hu = *(const uint2*)(h_bf + n * 64 + 2 * cg);
        float o0 = alpha * (cc.x + bv.x) + om * bflo(hu.x);
        float o1 = alpha * (cc.y + bv.y) + om * bfhi(hu.x);
        float o2 = alpha * (cc.z + bv.z) + om * bflo(hu.y);
        float o3 = alpha * (cc.w + bv.w) + om * bfhi(hu.y);
        float sm = o0 + o1 + o2 + o3;
#pragma unroll
        for (int mm = 1; mm < 32; mm <<= 1) sm += __shfl_xor(sm, mm);
        float mu = sm * (1.f / 128.f);
        float d0 = o0 - mu, d1 = o1 - mu, d2 = o2 - mu, d3 = o3 - mu;
        float sq = d0 * d0 + d1 * d1 + d2 * d2 + d3 * d3;
#pragma unroll
        for (int mm = 1; mm < 32; mm <<= 1) sq += __shfl_xor(sq, mm);
        float rs = rsqrtf(sq * (1.f / 128.f) + 1e-5f);
        uint2 o = make_uint2(
            bfpack(d0 * rs * g4.x + b4.x, d1 * rs * g4.y + b4.y),
            bfpack(d2 * rs * g4.z + b4.z, d3 * rs * g4.w + b4.w));
        *(uint2*)(h_bf + n * 64 + 2 * cg) = o;
    }
}

// ---- parallel masked mean-pool partials (batch sorted -> run-flush; h bf16) ----
__global__ __launch_bounds__(256) void pool_partial(
    const unsigned* __restrict__ h_bf, const float* __restrict__ x,
    const int* __restrict__ batch, float* __restrict__ psum, float* __restrict__ pcnt)
{
    const int c2 = threadIdx.x & 63;          // col pair 2c2, 2c2+1
    const int n0 = blockIdx.x * 64 + (threadIdx.x >> 6) * 16;
    int g = batch[n0];
    float sw0 = 0.f, sw1 = 0.f, sn0 = 0.f, sn1 = 0.f, cw = 0.f, cn = 0.f;
    for (int i = 0; i < 16; ++i) {
        int n = n0 + i;
        int gn = batch[n];
        if (gn != g) {
            atomicAdd(&psum[g * 256 + 2 * c2], sw0);
            atomicAdd(&psum[g * 256 + 2 * c2 + 1], sw1);
            atomicAdd(&psum[g * 256 + 128 + 2 * c2], sn0);
            atomicAdd(&psum[g * 256 + 128 + 2 * c2 + 1], sn1);
            if (c2 == 0) { atomicAdd(&pcnt[g * 2], cw); atomicAdd(&pcnt[g * 2 + 1], cn); }
            sw0 = sw1 = sn0 = sn1 = cw = cn = 0.f;
            g = gn;
        }
        float w = (x[(size_t)n * 5 + 1] > 0.f) ? 1.f : 0.f;
        unsigned u = h_bf[(size_t)n * 64 + c2];
        float h0 = bflo(u), h1 = bfhi(u);
        sw0 += w * h0; sw1 += w * h1;
        sn0 += (1.f - w) * h0; sn1 += (1.f - w) * h1;
        cw += w; cn += 1.f - w;
    }
    atomicAdd(&psum[g * 256 + 2 * c2], sw0);
    atomicAdd(&psum[g * 256 + 2 * c2 + 1], sw1);
    atomicAdd(&psum[g * 256 + 128 + 2 * c2], sn0);
    atomicAdd(&psum[g * 256 + 128 + 2 * c2 + 1], sn1);
    if (c2 == 0) { atomicAdd(&pcnt[g * 2], cw); atomicAdd(&pcnt[g * 2 + 1], cn); }
}

// ---------------- MLP head (pool finalize fused) ----------------
__global__ __launch_bounds__(256) void head_kernel(
    const float* __restrict__ psum, const float* __restrict__ pcnt,
    const float* __restrict__ task,
    const float* __restrict__ Wtf, const float* __restrict__ btf,
    const float* __restrict__ Wc1, const float* __restrict__ bc1,
    const float* __restrict__ Wc2, const float* __restrict__ bc2,
    float* __restrict__ out)
{
    __shared__ float in_s[640];
    __shared__ float ge_s[256];
    __shared__ float hc_s[64];
    const int b = blockIdx.x, t = threadIdx.x;
    if (t < 256) {
        float cnt = pcnt[b * 2 + (t >> 7)];
        float sv = psum[b * 256 + t];
        in_s[t] = (cnt > 0.f) ? sv / fmaxf(cnt, 1.f) : 0.f;
    }
    for (int i = t; i < 384; i += 256) in_s[256 + i] = task[b * 384 + i];
    __syncthreads();
    float acc = btf[t];
    for (int i = 0; i < 640; ++i) acc += in_s[i] * Wtf[i * 256 + t];
    ge_s[t] = fmaxf(acc, 0.f);
    __syncthreads();
    if (t < 64) {
        float a2 = bc1[t];
        for (int i = 0; i < 256; ++i) a2 += ge_s[i] * Wc1[i * 64 + t];
        hc_s[t] = fmaxf(a2, 0.f);
    }
    __syncthreads();
    if (t < 64) {
        float v = hc_s[t] * Wc2[t];
#pragma unroll
        for (int off = 32; off >= 1; off >>= 1) v += __shfl_down(v, off);
        if (t == 0) out[b] = v + bc2[0];
    }
}

__global__ __launch_bounds__(256) void zero_kernel(float4* __restrict__ p, int count4)
{
    int i = blockIdx.x * 256 + threadIdx.x;
    if (i < count4) p[i] = make_float4(0.f, 0.f, 0.f, 0.f);
}

extern "C" void kernel_launch(void* const* d_in, const int* in_sizes, int n_in,
                              void* d_out, int out_size, void* d_ws, size_t ws_size,
                              hipStream_t stream)
{
    const float* x      = (const float*)d_in[0];
    const int*   ast    = (const int*)d_in[1];
    const int*   batch  = (const int*)d_in[2];
    const int*   ei[3]  = {(const int*)d_in[3], (const int*)d_in[4], (const int*)d_in[5]};
    const float* task   = (const float*)d_in[6];
    const float* emb    = (const float*)d_in[7];
    const float* Win    = (const float*)d_in[8];
    const float* bin_   = (const float*)d_in[9];
    const float* Wkqv   = (const float*)d_in[10];
    const float* bkqv   = (const float*)d_in[11];
    const float* Wk_rel = (const float*)d_in[12];
    const float* Wv_rel = (const float*)d_in[13];
    const float* p_rel  = (const float*)d_in[14];
    const float* Wout   = (const float*)d_in[15];
    const float* bout   = (const float*)d_in[16];
    const float* skip   = (const float*)d_in[17];
    const float* ln_g   = (const float*)d_in[18];
    const float* ln_b   = (const float*)d_in[19];
    const float* Wtf    = (const float*)d_in[20];
    const float* btf    = (const float*)d_in[21];
    const float* Wc1    = (const float*)d_in[22];
    const float* bc1    = (const float*)d_in[23];
    const float* Wc2    = (const float*)d_in[24];
    const float* bc2    = (const float*)d_in[25];
    float* out = (float*)d_out;
    float* ws  = (float*)d_ws;

    unsigned* hB   = (unsigned*)(ws + OFF_HB);
    unsigned* P0   = (unsigned*)(ws + OFF_P0);   // q -> vt_0 -> vt_2
    unsigned* P1   = (unsigned*)(ws + OFF_P1);   // kt_r -> vt_1
    unsigned* AS   = (unsigned*)(ws + OFF_AS);
    float*    sbuf = ws + OFF_S;
    int*      rp   = (int*)(ws + OFF_RP);
    int*      csrc = (int*)(ws + OFF_CSRC);
    int*      cdst = (int*)(ws + OFF_CDST);
    int*      fill = (int*)(ws + OFF_P0);        // aliases P0 during CSR build only
    float*    Wf   = ws + OFF_WF;
    float*    bf   = ws + OFF_BF;
    int*      bs   = (int*)(ws + OFF_BS);
    float*    psum = ws + OFF_POOL;
    float*    pcnt = psum + (size_t)BB * 256;
    unsigned* WT   = (unsigned*)(ws + OFF_WT);   // 14 gemm slots + 2 Wout slots

    fold_weights<<<14, 256, 0, stream>>>(Wkqv, bkqv, Wk_rel, Wv_rel, Wf, bf);
    pack_wt<<<14, 256, 0, stream>>>(Wf, WT);
    pack_wt<<<2, 256, 0, stream>>>(Wout, WT + (size_t)14 * 8192);
    input_proj<<<NN / 16, 256, 0, stream>>>(x, ast, emb, Win, bin_, hB);

    zero_kernel<<<(600016 / 4 + 255) / 256, 256, 0, stream>>>((float4*)rp, 600016 / 4);
    zero_kernel<<<(600000 / 4 + 255) / 256, 256, 0, stream>>>((float4*)fill, 600000 / 4);
    csr_hist<<<(3 * EE + 255) / 256, 256, 0, stream>>>(ei[0], ei[1], ei[2], rp);
    scan1<<<dim3(SCAN_NB, 3), 256, 0, stream>>>(rp, bs);
    scan2<<<3, 128, 0, stream>>>(bs);
    scan3<<<dim3(SCAN_NB, 3), 256, 0, stream>>>(rp, bs);
    csr_scatter<<<(3 * EE + 255) / 256, 256, 0, stream>>>(
        ei[0], ei[1], ei[2], rp, fill, csrc, cdst);

    for (int l = 0; l < 2; ++l) {
        const size_t ls = (size_t)l * 7;   // slots: 0=q, 1..3=kt_r, 4..6=vt_r
        gemm_mfma<<<NN / 32, 256, 0, stream>>>(hB, WT + ls * 8192, bf + ls * 128, P0);
        for (int r = 0; r < 3; ++r) {
            gemm_mfma<<<NN / 32, 256, 0, stream>>>(
                hB, WT + (ls + 1 + r) * 8192, bf + (ls + 1 + r) * 128, P1);
            edge_scores_csr<<<(EE * 4 + 255) / 256, 256, 0, stream>>>(
                P0, P1, csrc + (size_t)r * EE, cdst + (size_t)r * EE,
                p_rel + (size_t)(l * 3 + r) * 4, sbuf + (size_t)r * EE * 4);
        }
        csr_softmax<<<NN / 4, 256, 0, stream>>>(sbuf, rp);
        // phase B: q dead -> P0 = vt_0; kt dead -> P1 = vt_1; then P0 = vt_2
        gemm_mfma<<<NN / 32, 256, 0, stream>>>(hB, WT + (ls + 4) * 8192, bf + (ls + 4) * 128, P0);
        gemm_mfma<<<NN / 32, 256, 0, stream>>>(hB, WT + (ls + 5) * 8192, bf + (ls + 5) * 128, P1);
        agg_reg<2, 1><<<NN / 4, 256, 0, stream>>>(P0, P1, sbuf, rp, csrc, 0, 1, AS);
        gemm_mfma<<<NN / 32, 256, 0, stream>>>(hB, WT + (ls + 6) * 8192, bf + (ls + 6) * 128, P0);
        agg_reg<1, 0><<<NN / 4, 256, 0, stream>>>(P0, P0, sbuf, rp, csrc, 2, 2, AS);
        out_ln<<<NN / 32, 256, 0, stream>>>(
            AS, hB, WT + (size_t)(14 + l) * 8192, bout + (size_t)l * 128,
            skip + l, ln_g + (size_t)l * 128, ln_b + (size_t)l * 128);
    }

    zero_kernel<<<(16512 / 4 + 255) / 256, 256, 0, stream>>>((float4*)psum, 16512 / 4);
    pool_partial<<<NN / 64, 256, 0, stream>>>(hB, x, batch, psum, pcnt);
    head_kernel<<<BB, 256, 0, stream>>>(psum, pcnt, task, Wtf, btf, Wc1, bc1, Wc2, bc2, out);
}